// Round 1
// baseline (1450.934 us; speedup 1.0000x reference)
//
#include <hip/hip_runtime.h>
#include <hip/hip_bf16.h>

#define NE 8
#define TT 2048
#define HD 2048
#define ID 4096

typedef __attribute__((ext_vector_type(8))) short bf16x8;
typedef __attribute__((ext_vector_type(4))) float f32x4;
typedef __attribute__((ext_vector_type(4))) unsigned int u32x4;
typedef __attribute__((ext_vector_type(2))) unsigned int u32x2;
typedef __attribute__((ext_vector_type(4))) unsigned short u16x4;

__device__ __forceinline__ unsigned short f2bf(float f) {
  unsigned int u = __builtin_bit_cast(unsigned int, f);
  u += 0x7FFFu + ((u >> 16) & 1u);   // round-to-nearest-even
  return (unsigned short)(u >> 16);
}

__global__ void init_kernel(int* counts) {
  if (threadIdx.x < NE) counts[threadIdx.x] = 0;
}

// One block per token: logits(8), argmax, sigmoid, router_scores out,
// per-expert token list append, and bf16 copies of x and x*score.
__global__ __launch_bounds__(256) void router_kernel(
    const float* __restrict__ x, const float* __restrict__ rw,
    float* __restrict__ rs_out, unsigned short* __restrict__ xb,
    unsigned short* __restrict__ xsb, int* __restrict__ counts,
    int* __restrict__ tlist) {
  const int t = blockIdx.x;
  const int tid = threadIdx.x;
  const float* xr = x + (size_t)t * HD;
  float acc[NE];
#pragma unroll
  for (int e = 0; e < NE; ++e) acc[e] = 0.f;
  for (int h = tid; h < HD; h += 256) {
    float xv = xr[h];
#pragma unroll
    for (int e = 0; e < NE; ++e) acc[e] += xv * rw[e * HD + h];
  }
#pragma unroll
  for (int e = 0; e < NE; ++e) {
#pragma unroll
    for (int off = 32; off > 0; off >>= 1) acc[e] += __shfl_down(acc[e], off);
  }
  __shared__ float part[4][NE];
  __shared__ int sE;
  __shared__ float sS;
  const int wave = tid >> 6, lane = tid & 63;
  if (lane == 0) {
#pragma unroll
    for (int e = 0; e < NE; ++e) part[wave][e] = acc[e];
  }
  __syncthreads();
  if (tid == 0) {
    float best = -3.4e38f;
    int be = 0;
#pragma unroll
    for (int e = 0; e < NE; ++e) {
      float v = part[0][e] + part[1][e] + part[2][e] + part[3][e];
      if (v > best) { best = v; be = e; }   // strict > keeps lowest index (top_k tie rule)
    }
    float s = 1.f / (1.f + expf(-best));
    sE = be;
    sS = s;
    int pos = atomicAdd(&counts[be], 1);
    tlist[be * TT + pos] = t;
  }
  __syncthreads();
  if (tid < NE) rs_out[tid * TT + t] = (tid == sE) ? sS : 0.f;
  const float s = sS;
  for (int h = tid; h < HD; h += 256) {
    float f = xr[h];
    xb[(size_t)t * HD + h] = f2bf(f);
    xsb[(size_t)t * HD + h] = f2bf(f * s);
  }
}

// Grouped gate_up GEMM. z = 0..7: routed expert e (A = xsb gathered rows,
// B = gate_up_proj[e], ldb = 2I, gate cols [0,I), up cols [I,2I)).
// z = 8: shared MLP (A = xb identity rows, B1 = shared_gate, B2 = shared_up).
// Epilogue: h = silu(g)*u -> bf16 h buffer (row = token id).
__global__ __launch_bounds__(256) void gateup_kernel(
    const unsigned short* __restrict__ xb, const unsigned short* __restrict__ xsb,
    const float* __restrict__ gup, const float* __restrict__ shg,
    const float* __restrict__ shu, const int* __restrict__ counts,
    const int* __restrict__ tlist, unsigned short* __restrict__ hsh,
    unsigned short* __restrict__ hrt) {
  const int bz = blockIdx.z;
  const bool sh = (bz == NE);
  const int cnt = sh ? TT : counts[bz];
  const int row0 = blockIdx.y * 128;
  if (row0 >= cnt) return;
  const int n0 = blockIdx.x * 64;
  const unsigned short* Aptr = sh ? xb : xsb;
  const float* B1;
  const float* B2;
  size_t ldb;
  if (sh) {
    B1 = shg + n0; B2 = shu + n0; ldb = ID;
  } else {
    const float* base = gup + (size_t)bz * HD * 2 * ID;
    B1 = base + n0; B2 = base + ID + n0; ldb = 2 * ID;
  }
  unsigned short* hout = sh ? hsh : hrt;

  __shared__ int toks[128];
  __shared__ __align__(16) unsigned short As[128][40];  // [m][k], pad->2-way (free)
  __shared__ __align__(16) unsigned short Bg[64][36];   // [n][k], stride 36 -> b64 conflict-light
  __shared__ __align__(16) unsigned short Bu[64][36];

  const int tid = threadIdx.x;
  if (tid < 128) {
    int r = row0 + tid;
    toks[tid] = (r < cnt) ? (sh ? r : tlist[bz * TT + r]) : -1;
  }
  __syncthreads();

  const int lane = tid & 63;
  const int wave = tid >> 6;
  const int wm = (wave >> 1) * 64, wn = (wave & 1) * 32;
  const int rA0 = tid >> 2, cA = (tid & 3) * 8, rA1 = rA0 + 64;
  const int tok0 = toks[rA0], tok1 = toks[rA1];
  const int nB = tid & 63;
  const int fm = lane & 15, q = lane >> 4;

  const f32x4 zf = {0.f, 0.f, 0.f, 0.f};
  f32x4 accg[4][2], accu[4][2];
#pragma unroll
  for (int a = 0; a < 4; ++a)
#pragma unroll
    for (int b = 0; b < 2; ++b) { accg[a][b] = zf; accu[a][b] = zf; }

  for (int k0 = 0; k0 < HD; k0 += 32) {
    // ---- stage A (bf16, coalesced 16B, gathered rows) ----
    u32x4 v0 = {0, 0, 0, 0}, v1 = {0, 0, 0, 0};
    if (tok0 >= 0) v0 = *(const u32x4*)(const void*)(Aptr + (size_t)tok0 * HD + k0 + cA);
    if (tok1 >= 0) v1 = *(const u32x4*)(const void*)(Aptr + (size_t)tok1 * HD + k0 + cA);
    *(u32x4*)(void*)&As[rA0][cA] = v0;
    *(u32x4*)(void*)&As[rA1][cA] = v1;
    // ---- stage B transposed: 4 coalesced f32 row-loads -> 4 bf16 -> b64 write ----
#pragma unroll
    for (int i = 0; i < 2; ++i) {
      const int kq = (tid >> 6) + 4 * i;  // 0..7
      const float* p1 = B1 + (size_t)(k0 + kq * 4) * ldb + nB;
      u16x4 w1;
      w1[0] = f2bf(p1[0]); w1[1] = f2bf(p1[ldb]);
      w1[2] = f2bf(p1[2 * ldb]); w1[3] = f2bf(p1[3 * ldb]);
      *(u16x4*)(void*)&Bg[nB][kq * 4] = w1;
      const float* p2 = B2 + (size_t)(k0 + kq * 4) * ldb + nB;
      u16x4 w2;
      w2[0] = f2bf(p2[0]); w2[1] = f2bf(p2[ldb]);
      w2[2] = f2bf(p2[2 * ldb]); w2[3] = f2bf(p2[3 * ldb]);
      *(u16x4*)(void*)&Bu[nB][kq * 4] = w2;
    }
    __syncthreads();
    // ---- fragments + MFMA ----
    bf16x8 af[4];
#pragma unroll
    for (int mt = 0; mt < 4; ++mt)
      af[mt] = __builtin_bit_cast(bf16x8,
               *(const u32x4*)(const void*)&As[wm + mt * 16 + fm][q * 8]);
    bf16x8 bgf[2], buf2[2];
#pragma unroll
    for (int nt = 0; nt < 2; ++nt) {
      const unsigned short* bp = &Bg[wn + nt * 16 + fm][q * 8];
      u32x2 lo = *(const u32x2*)(const void*)bp;
      u32x2 hi = *(const u32x2*)(const void*)(bp + 4);
      u32x4 v; v[0] = lo[0]; v[1] = lo[1]; v[2] = hi[0]; v[3] = hi[1];
      bgf[nt] = __builtin_bit_cast(bf16x8, v);
      const unsigned short* bp2 = &Bu[wn + nt * 16 + fm][q * 8];
      lo = *(const u32x2*)(const void*)bp2;
      hi = *(const u32x2*)(const void*)(bp2 + 4);
      v[0] = lo[0]; v[1] = lo[1]; v[2] = hi[0]; v[3] = hi[1];
      buf2[nt] = __builtin_bit_cast(bf16x8, v);
    }
#pragma unroll
    for (int mt = 0; mt < 4; ++mt)
#pragma unroll
      for (int nt = 0; nt < 2; ++nt) {
        accg[mt][nt] = __builtin_amdgcn_mfma_f32_16x16x32_bf16(af[mt], bgf[nt], accg[mt][nt], 0, 0, 0);
        accu[mt][nt] = __builtin_amdgcn_mfma_f32_16x16x32_bf16(af[mt], buf2[nt], accu[mt][nt], 0, 0, 0);
      }
    __syncthreads();
  }
  // ---- epilogue: silu(g)*u ----
#pragma unroll
  for (int mt = 0; mt < 4; ++mt)
#pragma unroll
    for (int nt = 0; nt < 2; ++nt)
#pragma unroll
      for (int r = 0; r < 4; ++r) {
        int ml = wm + mt * 16 + q * 4 + r;
        if (row0 + ml < cnt) {
          int tok = toks[ml];
          int n = n0 + wn + nt * 16 + fm;
          float g = accg[mt][nt][r], u = accu[mt][nt][r];
          float hv = g / (1.f + __expf(-g)) * u;
          hout[(size_t)tok * ID + n] = f2bf(hv);
        }
      }
}

// Down-proj GEMM. routed==0: A = hsh identity rows, out[t,n] = acc (dense write).
// routed==1: z = expert, A = hrt gathered rows, out[t,n] += acc (each token in
// exactly one expert list -> no write race; stream order after shared pass).
__global__ __launch_bounds__(256) void down_kernel(
    const unsigned short* __restrict__ Ah, const float* __restrict__ Bbase,
    const int* __restrict__ counts, const int* __restrict__ tlist,
    float* __restrict__ out, const int routed) {
  const int e = blockIdx.z;
  const int cnt = routed ? counts[e] : TT;
  const int row0 = blockIdx.y * 128;
  if (row0 >= cnt) return;
  const int n0 = blockIdx.x * 64;
  const float* B = routed ? (Bbase + (size_t)e * ID * HD + n0) : (Bbase + n0);

  __shared__ int toks[128];
  __shared__ __align__(16) unsigned short As[128][40];
  __shared__ __align__(16) unsigned short Bs[64][36];

  const int tid = threadIdx.x;
  if (tid < 128) {
    int r = row0 + tid;
    toks[tid] = (r < cnt) ? (routed ? tlist[e * TT + r] : r) : -1;
  }
  __syncthreads();

  const int lane = tid & 63, wave = tid >> 6;
  const int wm = (wave >> 1) * 64, wn = (wave & 1) * 32;
  const int rA0 = tid >> 2, cA = (tid & 3) * 8, rA1 = rA0 + 64;
  const int tok0 = toks[rA0], tok1 = toks[rA1];
  const int nB = tid & 63;
  const int fm = lane & 15, q = lane >> 4;

  const f32x4 zf = {0.f, 0.f, 0.f, 0.f};
  f32x4 acc[4][2];
#pragma unroll
  for (int a = 0; a < 4; ++a)
#pragma unroll
    for (int b = 0; b < 2; ++b) acc[a][b] = zf;

  for (int k0 = 0; k0 < ID; k0 += 32) {
    u32x4 v0 = {0, 0, 0, 0}, v1 = {0, 0, 0, 0};
    if (tok0 >= 0) v0 = *(const u32x4*)(const void*)(Ah + (size_t)tok0 * ID + k0 + cA);
    if (tok1 >= 0) v1 = *(const u32x4*)(const void*)(Ah + (size_t)tok1 * ID + k0 + cA);
    *(u32x4*)(void*)&As[rA0][cA] = v0;
    *(u32x4*)(void*)&As[rA1][cA] = v1;
#pragma unroll
    for (int i = 0; i < 2; ++i) {
      const int kq = (tid >> 6) + 4 * i;
      const float* p = B + (size_t)(k0 + kq * 4) * HD + nB;
      u16x4 w;
      w[0] = f2bf(p[0]); w[1] = f2bf(p[HD]);
      w[2] = f2bf(p[2 * HD]); w[3] = f2bf(p[3 * HD]);
      *(u16x4*)(void*)&Bs[nB][kq * 4] = w;
    }
    __syncthreads();
    bf16x8 af[4];
#pragma unroll
    for (int mt = 0; mt < 4; ++mt)
      af[mt] = __builtin_bit_cast(bf16x8,
               *(const u32x4*)(const void*)&As[wm + mt * 16 + fm][q * 8]);
    bf16x8 bfr[2];
#pragma unroll
    for (int nt = 0; nt < 2; ++nt) {
      const unsigned short* bp = &Bs[wn + nt * 16 + fm][q * 8];
      u32x2 lo = *(const u32x2*)(const void*)bp;
      u32x2 hi = *(const u32x2*)(const void*)(bp + 4);
      u32x4 v; v[0] = lo[0]; v[1] = lo[1]; v[2] = hi[0]; v[3] = hi[1];
      bfr[nt] = __builtin_bit_cast(bf16x8, v);
    }
#pragma unroll
    for (int mt = 0; mt < 4; ++mt)
#pragma unroll
      for (int nt = 0; nt < 2; ++nt)
        acc[mt][nt] = __builtin_amdgcn_mfma_f32_16x16x32_bf16(af[mt], bfr[nt], acc[mt][nt], 0, 0, 0);
    __syncthreads();
  }
#pragma unroll
  for (int mt = 0; mt < 4; ++mt)
#pragma unroll
    for (int nt = 0; nt < 2; ++nt)
#pragma unroll
      for (int r = 0; r < 4; ++r) {
        int ml = wm + mt * 16 + q * 4 + r;
        if (row0 + ml < cnt) {
          int tok = toks[ml];
          int n = n0 + wn + nt * 16 + fm;
          float v = acc[mt][nt][r];
          float* o = out + (size_t)tok * HD + n;
          if (routed) *o += v; else *o = v;
        }
      }
}

extern "C" void kernel_launch(void* const* d_in, const int* in_sizes, int n_in,
                              void* d_out, int out_size, void* d_ws, size_t ws_size,
                              hipStream_t stream) {
  const float* x   = (const float*)d_in[0];
  const float* rw  = (const float*)d_in[1];
  const float* gup = (const float*)d_in[2];
  const float* dwn = (const float*)d_in[3];
  const float* shg = (const float*)d_in[4];
  const float* shu = (const float*)d_in[5];
  const float* shd = (const float*)d_in[6];
  float* out = (float*)d_out;

  char* ws = (char*)d_ws;
  int* counts = (int*)ws;                                    // 32 B
  int* tlist = (int*)(ws + 1024);                            // 64 KB
  unsigned short* xb  = (unsigned short*)(ws + (1 << 17));               // 8 MB
  unsigned short* xsb = (unsigned short*)(ws + (1 << 17) + 8388608);     // 8 MB
  unsigned short* hsh = (unsigned short*)(ws + (1 << 17) + 16777216);    // 16 MB
  unsigned short* hrt = (unsigned short*)(ws + (1 << 17) + 33554432);    // 16 MB

  hipLaunchKernelGGL(init_kernel, dim3(1), dim3(64), 0, stream, counts);
  hipLaunchKernelGGL(router_kernel, dim3(TT), dim3(256), 0, stream,
                     x, rw, out + (size_t)TT * HD, xb, xsb, counts, tlist);
  hipLaunchKernelGGL(gateup_kernel, dim3(ID / 64, TT / 128, NE + 1), dim3(256), 0, stream,
                     xb, xsb, gup, shg, shu, counts, tlist, hsh, hrt);
  hipLaunchKernelGGL(down_kernel, dim3(HD / 64, TT / 128, 1), dim3(256), 0, stream,
                     hsh, shd, counts, tlist, out, 0);
  hipLaunchKernelGGL(down_kernel, dim3(HD / 64, TT / 128, NE), dim3(256), 0, stream,
                     hrt, dwn, counts, tlist, out, 1);
}